// Round 3
// baseline (367.788 us; speedup 1.0000x reference)
//
#include <hip/hip_runtime.h>
#include <hip/hip_fp16.h>

#define DIM 64
#define BN_EPS 1e-5f

// ---------------- degree: deg[dst[e]] += 1 (int4 edge reads) ----------------
__global__ void k_degree(const int* __restrict__ dst, int* __restrict__ deg, int E) {
    int e = blockIdx.x * blockDim.x + threadIdx.x;
    int E4 = E >> 2;
    if (e < E4) {
        int4 v = ((const int4*)dst)[e];
        atomicAdd(&deg[v.x], 1);
        atomicAdd(&deg[v.y], 1);
        atomicAdd(&deg[v.z], 1);
        atomicAdd(&deg[v.w], 1);
    }
    if (e < (E & 3)) atomicAdd(&deg[dst[(E4 << 2) + e]], 1);
}

// ---------------- scan stage 1: per-block exclusive scan + block sums + dinv ----------------
__global__ void k_scan1(const int* __restrict__ deg, int* __restrict__ rowptr,
                        int* __restrict__ bsum, float* __restrict__ dinv, int N) {
    __shared__ int s[256];
    int i = blockIdx.x * 256 + threadIdx.x;
    int v = (i < N) ? deg[i] : 0;
    if (i < N) dinv[i] = rsqrtf((float)v + 1.0f);  // +1 self-loop
    s[threadIdx.x] = v;
    __syncthreads();
    for (int off = 1; off < 256; off <<= 1) {
        int t = (threadIdx.x >= off) ? s[threadIdx.x - off] : 0;
        __syncthreads();
        s[threadIdx.x] += t;
        __syncthreads();
    }
    if (i < N) rowptr[i] = s[threadIdx.x] - v;  // exclusive
    if (threadIdx.x == 255) bsum[blockIdx.x] = s[255];
}

// ---------------- scan stage 2: scan block sums (single block, nb <= 512) ----------------
__global__ void k_scan2(const int* __restrict__ bsum, int* __restrict__ bofs,
                        int nb, int* __restrict__ rowptr, int N) {
    __shared__ int s[512];
    int v = ((int)threadIdx.x < nb) ? bsum[threadIdx.x] : 0;
    s[threadIdx.x] = v;
    __syncthreads();
    for (int off = 1; off < 512; off <<= 1) {
        int t = (threadIdx.x >= (unsigned)off) ? s[threadIdx.x - off] : 0;
        __syncthreads();
        s[threadIdx.x] += t;
        __syncthreads();
    }
    if ((int)threadIdx.x < nb) bofs[threadIdx.x] = s[threadIdx.x] - v;
    if ((int)threadIdx.x == nb - 1) rowptr[N] = s[threadIdx.x];  // total = E
}

// ---------------- scan stage 3: add block offsets; init bucket cursor ----------------
__global__ void k_scan3(int* __restrict__ rowptr, const int* __restrict__ bofs,
                        int* __restrict__ cursor, int N) {
    int i = blockIdx.x * 256 + threadIdx.x;
    if (i < N) {
        int r = rowptr[i] + bofs[blockIdx.x];
        rowptr[i] = r;
        cursor[i] = r;  // absolute cursor for bucket pass
    }
}

// ---------------- bucket: counting-sort edge sources by dst ----------------
__global__ void k_bucket(const int* __restrict__ src, const int* __restrict__ dst,
                         int* __restrict__ cursor, int* __restrict__ ssrc, int E) {
    int e = blockIdx.x * blockDim.x + threadIdx.x;
    int E4 = E >> 2;
    if (e < E4) {
        int4 d4 = ((const int4*)dst)[e];
        int4 s4 = ((const int4*)src)[e];
        ssrc[atomicAdd(&cursor[d4.x], 1)] = s4.x;
        ssrc[atomicAdd(&cursor[d4.y], 1)] = s4.y;
        ssrc[atomicAdd(&cursor[d4.z], 1)] = s4.z;
        ssrc[atomicAdd(&cursor[d4.w], 1)] = s4.w;
    }
    if (e < (E & 3)) {
        int idx = (E4 << 2) + e;
        ssrc[atomicAdd(&cursor[dst[idx]], 1)] = src[idx];
    }
}

// ---------------- h2 = fp16( (x @ W) * dinv[row] ) : row per thread ----------------
__global__ __launch_bounds__(256) void k_gemm(const float* __restrict__ x,
                                              const float* __restrict__ W,
                                              const float* __restrict__ dinv,
                                              __half* __restrict__ h2, int N) {
    __shared__ float Wl[DIM * DIM];
    for (int i = threadIdx.x; i < DIM * DIM; i += 256) Wl[i] = W[i];
    __syncthreads();
    int r = blockIdx.x * 256 + threadIdx.x;
    if (r >= N) return;
    const float4* xr4 = (const float4*)(x + (size_t)r * DIM);
    float4 acc[16];
#pragma unroll
    for (int j = 0; j < 16; ++j) acc[j] = make_float4(0.f, 0.f, 0.f, 0.f);
    for (int k0 = 0; k0 < 16; ++k0) {
        float4 xv = xr4[k0];
#pragma unroll
        for (int kk = 0; kk < 4; ++kk) {
            float xs = (&xv.x)[kk];
            const float4* wrow = (const float4*)(Wl + (k0 * 4 + kk) * DIM);
#pragma unroll
            for (int j = 0; j < 16; ++j) {
                float4 w = wrow[j];
                acc[j].x += xs * w.x;
                acc[j].y += xs * w.y;
                acc[j].z += xs * w.z;
                acc[j].w += xs * w.w;
            }
        }
    }
    float dr = dinv[r];
    float4* hr4 = (float4*)(h2 + (size_t)r * DIM);
    union { __half2 h[4]; float4 f4; } pack;
#pragma unroll
    for (int j = 0; j < 16; j += 2) {
        pack.h[0] = __float22half2_rn(make_float2(acc[j].x * dr, acc[j].y * dr));
        pack.h[1] = __float22half2_rn(make_float2(acc[j].z * dr, acc[j].w * dr));
        pack.h[2] = __float22half2_rn(make_float2(acc[j + 1].x * dr, acc[j + 1].y * dr));
        pack.h[3] = __float22half2_rn(make_float2(acc[j + 1].z * dr, acc[j + 1].w * dr));
        hr4[j >> 1] = pack.f4;
    }
}

// ---------------- pull-aggregate + bias + relu + BN partial sums ----------------
// wave per node (grid-stride), lane = feature; h2 rows pre-scaled by dinv[src]
__global__ __launch_bounds__(256) void k_aggregate(
        const int* __restrict__ rowptr, const int* __restrict__ ssrc,
        const float* __restrict__ dinv, const __half* __restrict__ h2,
        const float* __restrict__ b, float* __restrict__ out,
        float* __restrict__ gsum, float* __restrict__ gsumsq, int N) {
    __shared__ float s1[256], s2[256];
    const int lane = threadIdx.x & 63;
    const int wave = threadIdx.x >> 6;
    const float bf = b[lane];
    float lsum = 0.f, lsq = 0.f;
    for (int d = blockIdx.x * 4 + wave; d < N; d += gridDim.x * 4) {
        int beg = rowptr[d], end = rowptr[d + 1];
        int cnt = end - beg;
        float a0 = 0.f, a1 = 0.f, a2 = 0.f, a3 = 0.f;
        for (int base = 0; base < cnt; base += 64) {
            int nch = min(64, cnt - base);
            int sv = 0;
            if (lane < nch) sv = ssrc[beg + base + lane];
            int j = 0;
            for (; j + 3 < nch; j += 4) {
                int s0 = __shfl(sv, j, 64);
                int sA = __shfl(sv, j + 1, 64);
                int sB = __shfl(sv, j + 2, 64);
                int sC = __shfl(sv, j + 3, 64);
                a0 += __half2float(h2[(size_t)s0 * DIM + lane]);
                a1 += __half2float(h2[(size_t)sA * DIM + lane]);
                a2 += __half2float(h2[(size_t)sB * DIM + lane]);
                a3 += __half2float(h2[(size_t)sC * DIM + lane]);
            }
            for (; j < nch; ++j) {
                int s0 = __shfl(sv, j, 64);
                a0 += __half2float(h2[(size_t)s0 * DIM + lane]);
            }
        }
        size_t di = (size_t)d * DIM + lane;
        float dd = dinv[d];
        float self = __half2float(h2[di]);  // = h[d]*dinv[d]; self term = h[d]*dd*dd = self*dd
        float a = (((a0 + a1) + (a2 + a3)) + self) * dd + bf;
        a = fmaxf(a, 0.f);
        out[di] = a;
        lsum += a;
        lsq += a * a;
    }
    s1[threadIdx.x] = lsum;
    s2[threadIdx.x] = lsq;
    __syncthreads();
    if (threadIdx.x < 64) {
        float t1 = s1[threadIdx.x] + s1[threadIdx.x + 64] + s1[threadIdx.x + 128] + s1[threadIdx.x + 192];
        float t2 = s2[threadIdx.x] + s2[threadIdx.x + 64] + s2[threadIdx.x + 128] + s2[threadIdx.x + 192];
        atomicAdd(&gsum[threadIdx.x], t1);
        atomicAdd(&gsumsq[threadIdx.x], t2);
    }
}

// ---------------- finalize per-feature scale/shift ----------------
__global__ void k_stats(const float* __restrict__ gsum, const float* __restrict__ gsumsq,
                        const float* __restrict__ gamma, const float* __restrict__ beta,
                        float* __restrict__ scale, float* __restrict__ shift, int N) {
    int f = threadIdx.x;
    if (f < DIM) {
        float inv_n = 1.0f / (float)N;
        float mean = gsum[f] * inv_n;
        float var = gsumsq[f] * inv_n - mean * mean;
        float istd = rsqrtf(var + BN_EPS);
        float sc = gamma[f] * istd;
        scale[f] = sc;
        shift[f] = beta[f] - mean * sc;
    }
}

// ---------------- bn pass 2: out = a*scale + shift, float4, in-place ----------------
// stride is a multiple of 16 float4s (64 floats) so each thread's feature set is loop-invariant
__global__ void k_bn2(float4* __restrict__ a, const float* __restrict__ scale,
                      const float* __restrict__ shift, int total4) {
    int i = blockIdx.x * blockDim.x + threadIdx.x;
    int stride = gridDim.x * blockDim.x;  // 2048*256 = 524288 ≡ 0 (mod 16)
    int f4 = i & 15;
    float4 sc = ((const float4*)scale)[f4];
    float4 sh = ((const float4*)shift)[f4];
    for (; i < total4; i += stride) {
        float4 v = a[i];
        v.x = v.x * sc.x + sh.x;
        v.y = v.y * sc.y + sh.y;
        v.z = v.z * sc.z + sh.z;
        v.w = v.w * sc.w + sh.w;
        a[i] = v;
    }
}

extern "C" void kernel_launch(void* const* d_in, const int* in_sizes, int n_in,
                              void* d_out, int out_size, void* d_ws, size_t ws_size,
                              hipStream_t stream) {
    const float* x     = (const float*)d_in[0];
    const int*   ei    = (const int*)d_in[1];
    const float* W     = (const float*)d_in[2];
    const float* b     = (const float*)d_in[3];
    const float* gamma = (const float*)d_in[4];
    const float* beta  = (const float*)d_in[5];
    float* out = (float*)d_out;

    const int N = in_sizes[0] / DIM;  // 100000
    const int E = in_sizes[1] / 2;    // 1000000
    const int* esrc = ei;
    const int* edst = ei + E;
    const int NB = (N + 255) / 256;   // 391

    // workspace layout
    char* ws = (char*)d_ws;
    size_t off = 0;
    int* deg = (int*)(ws + off);      off += (size_t)N * sizeof(int);
    off = (off + 255) & ~(size_t)255;
    float* dinv = (float*)(ws + off); off += (size_t)N * sizeof(float);
    off = (off + 255) & ~(size_t)255;
    int* rowptr = (int*)(ws + off);   off += (size_t)(N + 1) * sizeof(int);
    off = (off + 255) & ~(size_t)255;
    int* cursor = (int*)(ws + off);   off += (size_t)N * sizeof(int);
    off = (off + 255) & ~(size_t)255;
    int* bsum = (int*)(ws + off);     off += (size_t)NB * sizeof(int);
    off = (off + 255) & ~(size_t)255;
    int* bofs = (int*)(ws + off);     off += (size_t)NB * sizeof(int);
    off = (off + 255) & ~(size_t)255;
    int* ssrc = (int*)(ws + off);     off += (size_t)E * sizeof(int);
    off = (off + 255) & ~(size_t)255;
    __half* h2 = (__half*)(ws + off); off += (size_t)N * DIM * sizeof(__half);
    off = (off + 255) & ~(size_t)255;
    float* gsum   = (float*)(ws + off);
    float* gsumsq = gsum + 64;
    float* scale  = gsum + 128;
    float* shift  = gsum + 192;

    hipMemsetAsync(deg, 0, (size_t)N * sizeof(int), stream);
    hipMemsetAsync(gsum, 0, 128 * sizeof(float), stream);

    k_degree<<<((E >> 2) + 255) / 256, 256, 0, stream>>>(edst, deg, E);
    k_scan1<<<NB, 256, 0, stream>>>(deg, rowptr, bsum, dinv, N);
    k_scan2<<<1, 512, 0, stream>>>(bsum, bofs, NB, rowptr, N);
    k_scan3<<<NB, 256, 0, stream>>>(rowptr, bofs, cursor, N);
    k_bucket<<<((E >> 2) + 255) / 256, 256, 0, stream>>>(esrc, edst, cursor, ssrc, E);
    k_gemm<<<NB, 256, 0, stream>>>(x, W, dinv, h2, N);
    k_aggregate<<<4096, 256, 0, stream>>>(rowptr, ssrc, dinv, h2, b, out, gsum, gsumsq, N);
    k_stats<<<1, 64, 0, stream>>>(gsum, gsumsq, gamma, beta, scale, shift, N);
    k_bn2<<<2048, 256, 0, stream>>>((float4*)out, scale, shift, N * DIM / 4);
}